// Round 1
// baseline (426.101 us; speedup 1.0000x reference)
//
#include <hip/hip_runtime.h>
#include <math.h>

#define BN 128
#define DN 1024
#define CN 32768
#define NCHUNK 512  // CN / 64 columns per block

// ---------------------------------------------------------------------------
// Kernel 1: fused  (a) em -> out_em copy  (b) scores GEMM tile (128 x 64)
//           (c) per-row partial stats {max, sumexp, cnt(s>20), sum(sel s)}
// block = 256 thr, grid = 512.  Thread (ty=t/16, tx=t%16) owns 8 rows x 4 cols.
// ---------------------------------------------------------------------------
__global__ __launch_bounds__(256)
void k1_gemm_stats(const float* __restrict__ inp, const float* __restrict__ em,
                   float* __restrict__ out_loss, float* __restrict__ out_em,
                   float* __restrict__ ws)
{
    __shared__ float As[32][132];  // [kk][row], padded (132w = 528B, 16B aligned rows)
    __shared__ float Bs[32][68];   // [kk][col], padded (272B rows)
    const int t   = threadIdx.x;
    const int blk = blockIdx.x;
    const int c0  = blk * 64;
    if (blk == 0 && t == 0) out_loss[0] = 0.0f;   // zero loss accumulator (repoisoned each launch)
    const int ty = t >> 4, tx = t & 15;

    float acc[8][4];
#pragma unroll
    for (int r = 0; r < 8; ++r)
#pragma unroll
        for (int c = 0; c < 4; ++c) acc[r][c] = 0.0f;

    for (int kt = 0; kt < DN; kt += 32) {
        // stage A tile: 128 rows x 32 k  (1024 float4, 4 per thread)
#pragma unroll
        for (int p = 0; p < 4; ++p) {
            int q = p * 256 + t;
            int row = q >> 3, kc4 = q & 7;
            float4 v = *(const float4*)&inp[(size_t)row * DN + kt + kc4 * 4];
            As[kc4 * 4 + 0][row] = v.x;
            As[kc4 * 4 + 1][row] = v.y;
            As[kc4 * 4 + 2][row] = v.z;
            As[kc4 * 4 + 3][row] = v.w;
        }
        // stage B tile: 64 em rows x 32 k, and copy em -> out_em on the way
#pragma unroll
        for (int p = 0; p < 2; ++p) {
            int q = p * 256 + t;
            int r = q >> 3, kc4 = q & 7;
            size_t gidx = (size_t)(c0 + r) * DN + kt + kc4 * 4;
            const float4 v = *(const float4*)&em[gidx];
            *(float4*)&out_em[gidx] = v;
            Bs[kc4 * 4 + 0][r] = v.x;
            Bs[kc4 * 4 + 1][r] = v.y;
            Bs[kc4 * 4 + 2][r] = v.z;
            Bs[kc4 * 4 + 3][r] = v.w;
        }
        __syncthreads();
#pragma unroll
        for (int kk = 0; kk < 32; ++kk) {
            float a[8], b[4];
            *(float4*)&a[0] = *(const float4*)&As[kk][ty * 8];
            *(float4*)&a[4] = *(const float4*)&As[kk][ty * 8 + 4];
            *(float4*)&b[0] = *(const float4*)&Bs[kk][tx * 4];
#pragma unroll
            for (int r = 0; r < 8; ++r)
#pragma unroll
                for (int c = 0; c < 4; ++c)
                    acc[r][c] = fmaf(a[r], b[c], acc[r][c]);
        }
        __syncthreads();
    }

    // per-row partial stats across this block's 64 columns.
    // Rows of thread = ty*8 + r; the 16 threads sharing ty are lanes (l&15).
#pragma unroll
    for (int r = 0; r < 8; ++r) {
        const int i = ty * 8 + r;
        float s[4];
#pragma unroll
        for (int c = 0; c < 4; ++c) s[c] = acc[r][c] * 20.0f;  // 1/TAU
        float m = fmaxf(fmaxf(s[0], s[1]), fmaxf(s[2], s[3]));
#pragma unroll
        for (int off = 1; off < 16; off <<= 1) m = fmaxf(m, __shfl_xor(m, off));
        float z = 0.f, cnt = 0.f, ss = 0.f;
#pragma unroll
        for (int c = 0; c < 4; ++c) {
            z += expf(s[c] - m);
            if (s[c] > 20.0f) { cnt += 1.0f; ss += s[c]; }  // LAMBDA0/TAU = 20
        }
#pragma unroll
        for (int off = 1; off < 16; off <<= 1) {
            z   += __shfl_xor(z, off);
            cnt += __shfl_xor(cnt, off);
            ss  += __shfl_xor(ss, off);
        }
        if (tx == 0) {
            float4 w = make_float4(m, z, cnt, ss);
            *(float4*)&ws[((size_t)i * NCHUNK + blk) * 4] = w;
        }
    }
}

// ---------------------------------------------------------------------------
// Kernel 2: per input row i (one block each): merge 512 chunk partials,
// recompute s_y = dot(inp[i], em[y])/TAU, emit ks[i] and atomicAdd loss/128.
// ---------------------------------------------------------------------------
__global__ __launch_bounds__(256)
void k2_finalize(const float* __restrict__ inp, const float* __restrict__ em,
                 const int* __restrict__ tgt, const float* __restrict__ ws,
                 float* __restrict__ d_loss, float* __restrict__ d_ks)
{
    const int i = blockIdx.x;
    const int t = threadIdx.x;
    const int wid = t >> 6, lane = t & 63;
    __shared__ float red[4][4];
    __shared__ float dred[4];

    // merge chunk partials (2 per thread)
    float m = -INFINITY, z = 0.f, cnt = 0.f, ss = 0.f;
    for (int c = t; c < NCHUNK; c += 256) {
        float4 w = *(const float4*)&ws[((size_t)i * NCHUNK + c) * 4];
        float M = fmaxf(m, w.x);
        z = z * expf(m - M) + w.y * expf(w.x - M);
        m = M;
        cnt += w.z; ss += w.w;
    }
#pragma unroll
    for (int off = 1; off < 64; off <<= 1) {
        float m2 = __shfl_xor(m, off), z2 = __shfl_xor(z, off);
        float M = fmaxf(m, m2);
        z = z * expf(m - M) + z2 * expf(m2 - M);
        m = M;
        cnt += __shfl_xor(cnt, off);
        ss  += __shfl_xor(ss, off);
    }
    if (lane == 0) { red[wid][0] = m; red[wid][1] = z; red[wid][2] = cnt; red[wid][3] = ss; }

    // s_y dot product: 4 elems per thread
    const int y = tgt[i];
    float4 a = *(const float4*)&inp[(size_t)i * DN + t * 4];
    float4 b = *(const float4*)&em[(size_t)y * DN + t * 4];
    float d = a.x * b.x + a.y * b.y + a.z * b.z + a.w * b.w;
#pragma unroll
    for (int off = 1; off < 64; off <<= 1) d += __shfl_xor(d, off);
    if (lane == 0) dred[wid] = d;
    __syncthreads();

    if (t == 0) {
        float M = red[0][0], Z = red[0][1], CNT = red[0][2], SS = red[0][3];
#pragma unroll
        for (int w = 1; w < 4; ++w) {
            float m2 = red[w][0], z2 = red[w][1];
            float Mn = fmaxf(M, m2);
            Z = Z * expf(M - Mn) + z2 * expf(m2 - Mn);
            M = Mn; CNT += red[w][2]; SS += red[w][3];
        }
        float sy  = (dred[0] + dred[1] + dred[2] + dred[3]) * 20.0f;
        float lse = M + logf(Z);
        float A   = SS - CNT * lse;                       // sum over selected of (s - lse)
        float ki  = (CNT > 1.0f) ? (1.0f / (CNT * logf(CNT))) : 0.0f;
        float sum_t = ki * (A - ((sy > 20.0f) ? (sy - lse) : 0.0f)) + (sy - lse);
        atomicAdd(d_loss, -sum_t * (1.0f / 128.0f));
        d_ks[i] = CNT;
    }
}

// ---------------------------------------------------------------------------
// Kernel 3: sequential EMA chains. Block j acts only if j is the FIRST
// occurrence of target y; it then applies all occurrences in order
// (preserves jax.lax.scan semantics incl. duplicate targets).
// ---------------------------------------------------------------------------
__global__ __launch_bounds__(256)
void k3_ema(const float* __restrict__ inp, const int* __restrict__ tgt,
            const void* __restrict__ epoch_p, float* __restrict__ out_em)
{
    const int j = blockIdx.x;
    const int y = tgt[j];
    for (int p = 0; p < j; ++p)
        if (tgt[p] == y) return;  // not first occurrence (block-uniform)

    // decode epoch scalar robustly (int32 expected; float fallback)
    int ei = *(const int*)epoch_p;
    float e = (ei >= 0 && ei < 1000000) ? (float)ei : *(const float*)epoch_p;
    const float mu = fminf(0.4f / 60.0f * (e + 1.0f), 1.0f);
    const float om = 1.0f - mu;

    const int t = threadIdx.x;
    const int wid = t >> 6, lane = t & 63;
    __shared__ float nred[4];

    float4 r = *(const float4*)&out_em[(size_t)y * DN + t * 4];  // k1 already copied em
    for (int p = j; p < BN; ++p) {
        if (tgt[p] != y) continue;
        float4 x = *(const float4*)&inp[(size_t)p * DN + t * 4];
        r.x = mu * r.x + om * x.x;
        r.y = mu * r.y + om * x.y;
        r.z = mu * r.z + om * x.z;
        r.w = mu * r.w + om * x.w;
        float n = r.x * r.x + r.y * r.y + r.z * r.z + r.w * r.w;
#pragma unroll
        for (int off = 1; off < 64; off <<= 1) n += __shfl_xor(n, off);
        if (lane == 0) nred[wid] = n;
        __syncthreads();
        n = nred[0] + nred[1] + nred[2] + nred[3];
        float inv = 1.0f / sqrtf(n);
        r.x *= inv; r.y *= inv; r.z *= inv; r.w *= inv;
        __syncthreads();
    }
    *(float4*)&out_em[(size_t)y * DN + t * 4] = r;
}

extern "C" void kernel_launch(void* const* d_in, const int* in_sizes, int n_in,
                              void* d_out, int out_size, void* d_ws, size_t ws_size,
                              hipStream_t stream)
{
    const float* inp = (const float*)d_in[0];
    const float* em  = (const float*)d_in[1];
    const int*   tgt = (const int*)d_in[2];
    const void*  ep  = d_in[3];

    float* loss   = (float*)d_out;       // [1]
    float* ks     = loss + 1;            // [128]
    float* out_em = ks + BN;             // [32768*1024]
    float* ws     = (float*)d_ws;        // 128*512*4 floats = 1 MB partials

    k1_gemm_stats<<<512, 256, 0, stream>>>(inp, em, loss, out_em, ws);
    k2_finalize<<<128, 256, 0, stream>>>(inp, em, tgt, ws, loss, ks);
    k3_ema<<<128, 256, 0, stream>>>(inp, tgt, ep, out_em);
}

// Round 4
// 343.496 us; speedup vs baseline: 1.2405x; 1.2405x over previous
//
#include <hip/hip_runtime.h>
#include <math.h>

#define BN 128
#define DN 1024
#define CN 32768
#define NB 64              // em cols (classes) per block
#define KS 32              // k per step
#define NBLK (CN / NB)     // 512 blocks
#define LDA 40             // LDS row pitch in bf16 elems (80B, 16B-aligned)

typedef float f32x4 __attribute__((ext_vector_type(4)));
typedef short short8 __attribute__((ext_vector_type(8)));

static __device__ inline unsigned short f2b(float f) {
    union { float f; unsigned u; } v; v.f = f;
    unsigned r = v.u + 0x7FFF + ((v.u >> 16) & 1);   // RNE
    return (unsigned short)(r >> 16);
}

// ---------------------------------------------------------------------------
// k1: bf16-MFMA scores GEMM (128 x 64 tile per block over K=1024) fused with
//     em -> out_em copy and per-row {max, sumexp, cnt, sumsel} partials.
// 256 thr = 4 waves; wave w owns 16 cols x all 128 rows (8 M-tiles).
// ---------------------------------------------------------------------------
__global__ __launch_bounds__(256)
void k1_gemm_stats(const float* __restrict__ inp, const float* __restrict__ em,
                   float* __restrict__ out_loss, float* __restrict__ out_em,
                   float* __restrict__ ws)
{
    __shared__ unsigned short Ab[2][BN * LDA];   // 2 x 128x40 bf16 = 20.0 KB
    __shared__ unsigned short Bb[2][NB * LDA];   // 2 x  64x40 bf16 = 10.0 KB
    __shared__ float4 smp[BN][4];                // per-wave stat partials, 8 KB

    const int t   = threadIdx.x;
    const int blk = blockIdx.x;
    const size_t c0 = (size_t)blk * NB;
    if (blk == 0 && t == 0) out_loss[0] = 0.0f;

    const int w  = t >> 6;
    const int l  = t & 63;
    const int lr = l & 15, lq = l >> 4;

    f32x4 acc[8];
#pragma unroll
    for (int m = 0; m < 8; ++m) acc[m] = (f32x4)0.0f;

    // staging index precompute (thread-constant)
    const int arow[4] = { (0*256 + t) >> 3, (1*256 + t) >> 3, (2*256 + t) >> 3, (3*256 + t) >> 3 };
    const int ak4     = t & 7;
    const int bcol[2] = { (0*256 + t) >> 3, (1*256 + t) >> 3 };

    float4 ga0[4], gb0[2], ga1[4], gb1[2];

#define LOADG(kt, GA, GB)                                                         \
    {                                                                             \
        _Pragma("unroll")                                                         \
        for (int p = 0; p < 4; ++p)                                               \
            GA[p] = *(const float4*)&inp[(size_t)arow[p] * DN + (kt) + ak4 * 4];  \
        _Pragma("unroll")                                                         \
        for (int p = 0; p < 2; ++p)                                               \
            GB[p] = *(const float4*)&em[(c0 + bcol[p]) * DN + (kt) + ak4 * 4];    \
    }

#define STAGE(buf, kt, GA, GB)                                                    \
    {                                                                             \
        _Pragma("unroll")                                                         \
        for (int p = 0; p < 4; ++p) {                                             \
            uint2 u;                                                              \
            u.x = (unsigned)f2b(GA[p].x) | ((unsigned)f2b(GA[p].y) << 16);        \
            u.y = (unsigned)f2b(GA[p].z) | ((unsigned)f2b(GA[p].w) << 16);        \
            *(uint2*)&Ab[buf][arow[p] * LDA + ak4 * 4] = u;                       \
        }                                                                         \
        _Pragma("unroll")                                                         \
        for (int p = 0; p < 2; ++p) {                                             \
            uint2 u;                                                              \
            u.x = (unsigned)f2b(GB[p].x) | ((unsigned)f2b(GB[p].y) << 16);        \
            u.y = (unsigned)f2b(GB[p].z) | ((unsigned)f2b(GB[p].w) << 16);        \
            *(uint2*)&Bb[buf][bcol[p] * LDA + ak4 * 4] = u;                       \
            *(float4*)&out_em[(c0 + bcol[p]) * DN + (kt) + ak4 * 4] = GB[p];      \
        }                                                                         \
    }

#define COMPUTE(buf)                                                              \
    {                                                                             \
        const short8 bf = *(const short8*)&Bb[buf][(w * 16 + lr) * LDA + lq * 8]; \
        _Pragma("unroll")                                                         \
        for (int m = 0; m < 8; ++m) {                                             \
            const short8 af = *(const short8*)&Ab[buf][(m * 16 + lr) * LDA + lq * 8]; \
            acc[m] = __builtin_amdgcn_mfma_f32_16x16x32_bf16(af, bf, acc[m], 0, 0, 0); \
        }                                                                         \
    }

    LOADG(0, ga0, gb0)
    for (int kt = 0; kt < DN; kt += 2 * KS) {
        STAGE(0, kt, ga0, gb0)
        __syncthreads();
        LOADG(kt + KS, ga1, gb1)
        COMPUTE(0)

        STAGE(1, kt + KS, ga1, gb1)
        __syncthreads();
        if (kt + 2 * KS < DN) LOADG(kt + 2 * KS, ga0, gb0)
        COMPUTE(1)
    }
    __syncthreads();

    // per-row stats over this block's 64 cols.
    // acc[m][r] is score for row = m*16 + lq*4 + r, col = c0 + w*16 + lr.
#pragma unroll
    for (int m = 0; m < 8; ++m) {
#pragma unroll
        for (int r = 0; r < 4; ++r) {
            float s = acc[m][r] * 20.0f;                       // 1/TAU
            float mx = s;
#pragma unroll
            for (int off = 1; off < 16; off <<= 1) mx = fmaxf(mx, __shfl_xor(mx, off));
            float z   = __expf(s - mx);
            float cnt = (s > 20.0f) ? 1.0f : 0.0f;             // LAMBDA0/TAU
            float ss  = (s > 20.0f) ? s : 0.0f;
#pragma unroll
            for (int off = 1; off < 16; off <<= 1) {
                z   += __shfl_xor(z, off);
                cnt += __shfl_xor(cnt, off);
                ss  += __shfl_xor(ss, off);
            }
            if (lr == 0) smp[m * 16 + lq * 4 + r][w] = make_float4(mx, z, cnt, ss);
        }
    }
    __syncthreads();

    // merge 4 wave-partials per row -> ws[row*NBLK + blk]
    if (t < BN) {
        float4 p0 = smp[t][0];
        float M = p0.x, Z = p0.y, CNT = p0.z, SS = p0.w;
#pragma unroll
        for (int q = 1; q < 4; ++q) {
            float4 p = smp[t][q];
            float Mn = fmaxf(M, p.x);
            Z = Z * __expf(M - Mn) + p.y * __expf(p.x - Mn);
            M = Mn; CNT += p.z; SS += p.w;
        }
        ((float4*)ws)[(size_t)t * NBLK + blk] = make_float4(M, Z, CNT, SS);
    }
}

// ---------------------------------------------------------------------------
// k2: per row i: merge NBLK chunk partials, recompute s_y, emit ks + loss.
// ---------------------------------------------------------------------------
__global__ __launch_bounds__(256)
void k2_finalize(const float* __restrict__ inp, const float* __restrict__ em,
                 const int* __restrict__ tgt, const float* __restrict__ ws,
                 float* __restrict__ d_loss, float* __restrict__ d_ks)
{
    const int i = blockIdx.x;
    const int t = threadIdx.x;
    const int wid = t >> 6, lane = t & 63;
    __shared__ float red[4][4];
    __shared__ float dred[4];

    float m = -INFINITY, z = 0.f, cnt = 0.f, ss = 0.f;
    for (int c = t; c < NBLK; c += 256) {
        float4 wv = ((const float4*)ws)[(size_t)i * NBLK + c];
        float M = fmaxf(m, wv.x);
        z = z * __expf(m - M) + wv.y * __expf(wv.x - M);
        m = M; cnt += wv.z; ss += wv.w;
    }
#pragma unroll
    for (int off = 1; off < 64; off <<= 1) {
        float m2 = __shfl_xor(m, off), z2 = __shfl_xor(z, off);
        float M = fmaxf(m, m2);
        z = z * __expf(m - M) + z2 * __expf(m2 - M);
        m = M;
        cnt += __shfl_xor(cnt, off);
        ss  += __shfl_xor(ss, off);
    }
    if (lane == 0) { red[wid][0] = m; red[wid][1] = z; red[wid][2] = cnt; red[wid][3] = ss; }

    const int y = tgt[i];
    float4 a = *(const float4*)&inp[(size_t)i * DN + t * 4];
    float4 b = *(const float4*)&em[(size_t)y * DN + t * 4];
    float d = a.x * b.x + a.y * b.y + a.z * b.z + a.w * b.w;
#pragma unroll
    for (int off = 1; off < 64; off <<= 1) d += __shfl_xor(d, off);
    if (lane == 0) dred[wid] = d;
    __syncthreads();

    if (t == 0) {
        float M = red[0][0], Z = red[0][1], CNT = red[0][2], SS = red[0][3];
#pragma unroll
        for (int q = 1; q < 4; ++q) {
            float m2 = red[q][0], z2 = red[q][1];
            float Mn = fmaxf(M, m2);
            Z = Z * __expf(M - Mn) + z2 * __expf(m2 - Mn);
            M = Mn; CNT += red[q][2]; SS += red[q][3];
        }
        float sy  = (dred[0] + dred[1] + dred[2] + dred[3]) * 20.0f;
        float lse = M + logf(Z);
        float A   = SS - CNT * lse;
        float ki  = (CNT > 1.0f) ? (1.0f / (CNT * logf(CNT))) : 0.0f;
        float sum_t = ki * (A - ((sy > 20.0f) ? (sy - lse) : 0.0f)) + (sy - lse);
        atomicAdd(d_loss, -sum_t * (1.0f / 128.0f));
        d_ks[i] = CNT;
    }
}

// ---------------------------------------------------------------------------
// k3: sequential EMA chains (first-occurrence block owns the chain).
// ---------------------------------------------------------------------------
__global__ __launch_bounds__(256)
void k3_ema(const float* __restrict__ inp, const int* __restrict__ tgt,
            const void* __restrict__ epoch_p, float* __restrict__ out_em)
{
    const int j = blockIdx.x;
    const int y = tgt[j];
    for (int p = 0; p < j; ++p)
        if (tgt[p] == y) return;

    int ei = *(const int*)epoch_p;
    float e = (ei >= 0 && ei < 1000000) ? (float)ei : *(const float*)epoch_p;
    const float mu = fminf(0.4f / 60.0f * (e + 1.0f), 1.0f);
    const float om = 1.0f - mu;

    const int t = threadIdx.x;
    const int wid = t >> 6, lane = t & 63;
    __shared__ float nred[4];

    float4 r = *(const float4*)&out_em[(size_t)y * DN + t * 4];
    for (int p = j; p < BN; ++p) {
        if (tgt[p] != y) continue;
        float4 x = *(const float4*)&inp[(size_t)p * DN + t * 4];
        r.x = mu * r.x + om * x.x;
        r.y = mu * r.y + om * x.y;
        r.z = mu * r.z + om * x.z;
        r.w = mu * r.w + om * x.w;
        float n = r.x * r.x + r.y * r.y + r.z * r.z + r.w * r.w;
#pragma unroll
        for (int off = 1; off < 64; off <<= 1) n += __shfl_xor(n, off);
        if (lane == 0) nred[wid] = n;
        __syncthreads();
        n = nred[0] + nred[1] + nred[2] + nred[3];
        float inv = 1.0f / sqrtf(n);
        r.x *= inv; r.y *= inv; r.z *= inv; r.w *= inv;
        __syncthreads();
    }
    *(float4*)&out_em[(size_t)y * DN + t * 4] = r;
}

extern "C" void kernel_launch(void* const* d_in, const int* in_sizes, int n_in,
                              void* d_out, int out_size, void* d_ws, size_t ws_size,
                              hipStream_t stream)
{
    const float* inp = (const float*)d_in[0];
    const float* em  = (const float*)d_in[1];
    const int*   tgt = (const int*)d_in[2];
    const void*  ep  = d_in[3];

    float* loss   = (float*)d_out;       // [1]
    float* ks     = loss + 1;            // [128]
    float* out_em = ks + BN;             // [32768*1024]
    float* ws     = (float*)d_ws;        // 128*512 float4 = 1 MB partials

    k1_gemm_stats<<<NBLK, 256, 0, stream>>>(inp, em, loss, out_em, ws);
    k2_finalize<<<BN, 256, 0, stream>>>(inp, em, tgt, ws, loss, ks);
    k3_ema<<<BN, 256, 0, stream>>>(inp, tgt, ep, out_em);
}